// Round 10
// baseline (5341.065 us; speedup 1.0000x reference)
//
#include <hip/hip_runtime.h>
#include <hip/hip_bf16.h>
#include <cstdint>

#define DEV __device__ __forceinline__

typedef __attribute__((ext_vector_type(8))) short short8;
typedef __attribute__((ext_vector_type(4))) short short4v;
typedef __attribute__((ext_vector_type(4))) float f32x4;

DEV float bf2f(ushort u){ union{ unsigned int i; float f;} c; c.i = ((unsigned int)u)<<16; return c.f; }
DEV ushort f2bf(float f){
  unsigned int r;
  asm("v_cvt_pk_bf16_f32 %0, %1, %1" : "=v"(r) : "v"(f));
  return (ushort)r;
}
DEV unsigned int f2bf2(float lo, float hi){
  unsigned int r;
  asm("v_cvt_pk_bf16_f32 %0, %1, %2" : "=v"(r) : "v"(lo), "v"(hi));
  return r;
}
// branch-free gelu: A&S 7.1.26 erf approx, |err|<=1.5e-7
DEV float gelu_f(float v){
  float a = fabsf(v)*0.7071067811865476f;
  float t = __builtin_amdgcn_rcpf(fmaf(0.3275911f, a, 1.f));
  float p = t*(0.254829592f + t*(-0.284496736f + t*(1.421413741f + t*(-1.453152027f + t*1.061405429f))));
  float e = __expf(-a*a);
  float er = fmaf(-p, e, 1.f);
  float sgn = (v < 0.f) ? -er : er;
  return 0.5f*v*(1.f+sgn);
}

DEV void gld_lds16(const void* g, void* l){
  __builtin_amdgcn_global_load_lds(
      (const __attribute__((address_space(1))) unsigned int*)g,
      (__attribute__((address_space(3))) unsigned int*)l, 16, 0, 0);
}

// ---------------------------------------------------------------------------
// Generic bf16 MFMA GEMM (optionally batched over blockIdx.z):
// C[M,N] = epi(A[M,K] @ W^T[N,K] + bias ...). 128x128 tile, BK=64.
// T2 chunk16 XOR swizzle on LDS; T1 XCD-aware block swizzle.
// ---------------------------------------------------------------------------
enum { EPI_NONE=0, EPI_GELU=1, EPI_COND=2, EPI_RESID=3 };

template<int EPI, bool OUTF32>
__global__ __launch_bounds__(256,2) void gemm_k(
    const ushort* __restrict__ A, const ushort* __restrict__ Wt,
    void* __restrict__ Cp, const float* __restrict__ bias,
    const ushort* __restrict__ resid,
    const int* __restrict__ uid, const int* __restrict__ scr,
    const float* __restrict__ utab, const float* __restrict__ stab,
    int M, int N, int K, int ldc, long a_bs, long w_bs, long c_bs)
{
  __shared__ __align__(16) ushort As[128*64];
  __shared__ __align__(16) ushort Ws[128*64];
  A  += (size_t)blockIdx.z * a_bs;
  Wt += (size_t)blockIdx.z * w_bs;
  ushort* Cb = (ushort*)Cp + (size_t)blockIdx.z * c_bs;
  const int flat = blockIdx.y*gridDim.x + blockIdx.x;
  const int nwg  = gridDim.x*gridDim.y;
  const int swz  = (flat & 7)*(nwg >> 3) + (flat >> 3);
  const int n0 = (swz % gridDim.x)*128, m0 = (swz / gridDim.x)*128;
  const int t = threadIdx.x;
  const int w = t>>6, lane=t&63, lr=lane&15, lh=lane>>4;
  const int wm=(w>>1)*64, wn=(w&1)*64;
  f32x4 acc[4][4] = {};
  for (int k0=0;k0<K;k0+=64){
    #pragma unroll
    for (int i=0;i<4;i++){
      int f=i*256+t; int r=f>>3, c=f&7;
      gld_lds16(A + (size_t)(m0+r)*K + k0 + ((c^(r&7))*8), &As[f*8]);
    }
    #pragma unroll
    for (int i=0;i<4;i++){
      int f=i*256+t; int r=f>>3, c=f&7;
      gld_lds16(Wt + (size_t)(n0+r)*K + k0 + ((c^(r&7))*8), &Ws[f*8]);
    }
    __syncthreads();
    #pragma unroll
    for (int kk=0;kk<64;kk+=32){
      const int c = (kk>>3) + lh;
      short8 af[4], bfr[4];
      #pragma unroll
      for (int mi=0;mi<4;mi++){ int row=wm+mi*16+lr; af[mi]  = *(const short8*)&As[row*64 + ((c^(row&7))*8)]; }
      #pragma unroll
      for (int ni=0;ni<4;ni++){ int row=wn+ni*16+lr; bfr[ni] = *(const short8*)&Ws[row*64 + ((c^(row&7))*8)]; }
      #pragma unroll
      for (int mi=0;mi<4;mi++)
        #pragma unroll
        for (int ni=0;ni<4;ni++)
          acc[mi][ni] = __builtin_amdgcn_mfma_f32_16x16x32_bf16(af[mi], bfr[ni], acc[mi][ni], 0,0,0);
    }
    __syncthreads();
  }
  #pragma unroll
  for (int mi=0;mi<4;mi++){
    #pragma unroll
    for (int ni=0;ni<4;ni++){
      #pragma unroll
      for (int r=0;r<4;r++){
        int m = m0 + wm + mi*16 + lh*4 + r;
        int n = n0 + wn + ni*16 + lr;
        float v = acc[mi][ni][r];
        if (bias) v += bias[n];
        if (EPI==EPI_GELU) v = gelu_f(v);
        if (EPI==EPI_COND) v += utab[(size_t)uid[m]*1024 + n] + stab[(size_t)scr[m]*1024 + n];
        if (EPI==EPI_RESID) v += bf2f(resid[(size_t)m*ldc + n]);
        if (OUTF32) ((float*)Cp)[(size_t)m*ldc + n] = v;
        else        Cb[(size_t)m*ldc + n] = f2bf(v);
      }
    }
  }
}

// ---------------------------------------------------------------------------
// Fused encoder front-half, per 128-row tile (N=K=128 throughout).
// ---------------------------------------------------------------------------
__global__ __launch_bounds__(256,2) void enc_fused_k(
    const ushort* __restrict__ CG, const ushort* __restrict__ Wca, const float* __restrict__ Bca,
    const ushort* __restrict__ Wen, const float* __restrict__ Ben,
    ushort* __restrict__ XG,
    const float* __restrict__ gcng, const float* __restrict__ gcnb,
    const float* __restrict__ ln1g, const float* __restrict__ ln1b,
    const float* __restrict__ ln2g, const float* __restrict__ ln2b,
    ushort* __restrict__ P, ushort* __restrict__ T2)
{
  __shared__ __align__(16) ushort As[128*128]; // CG tile, then T1
  __shared__ __align__(16) ushort Ws[128*128]; // Wca, then Wen
  const int t = threadIdx.x;
  const int m0 = blockIdx.x*128;
  const int w = t>>6, lane=t&63, lr=lane&15, lh=lane>>4;
  const int wm = w*32;
  #pragma unroll
  for (int i=0;i<8;i++){
    int f=i*256+t; int r=f>>4, c=f&15;
    gld_lds16(CG + (size_t)(m0+r)*128 + ((c^(r&7))*8), &As[f*8]);
  }
  #pragma unroll
  for (int i=0;i<8;i++){
    int f=i*256+t; int r=f>>4, c=f&15;
    gld_lds16(Wca + (size_t)r*128 + ((c^(r&7))*8), &Ws[f*8]);
  }
  __syncthreads();
  f32x4 acc[2][8] = {};
  #pragma unroll
  for (int kk=0;kk<128;kk+=32){
    const int c = (kk>>3) + lh;
    short8 af[2], bfr[8];
    #pragma unroll
    for (int mi=0;mi<2;mi++){ int row=wm+mi*16+lr; af[mi]  = *(const short8*)&As[row*128 + ((c^(row&7))*8)]; }
    #pragma unroll
    for (int ni=0;ni<8;ni++){ int row=ni*16+lr;    bfr[ni] = *(const short8*)&Ws[row*128 + ((c^(row&7))*8)]; }
    #pragma unroll
    for (int mi=0;mi<2;mi++)
      #pragma unroll
      for (int ni=0;ni<8;ni++)
        acc[mi][ni] = __builtin_amdgcn_mfma_f32_16x16x32_bf16(af[mi], bfr[ni], acc[mi][ni], 0,0,0);
  }
  __syncthreads();
  #pragma unroll
  for (int i=0;i<8;i++){
    int f=i*256+t; int r=f>>4, c=f&15;
    gld_lds16(Wen + (size_t)r*128 + ((c^(r&7))*8), &Ws[f*8]);
  }
  #pragma unroll
  for (int mi=0;mi<2;mi++){
    #pragma unroll
    for (int r=0;r<4;r++){
      const int ml = wm + mi*16 + lh*4 + r;
      const int m  = m0 + ml;
      float xv[8]; float s=0.f, ss=0.f;
      #pragma unroll
      for (int ni=0;ni<8;ni++){
        int n = ni*16+lr;
        float v = acc[mi][ni][r] + Bca[n] + bf2f(XG[(size_t)m*128+n]);
        xv[ni]=v; s+=v; ss+=v*v;
      }
      #pragma unroll
      for (int mk=1;mk<16;mk<<=1){ s += __shfl_xor(s,mk); ss += __shfl_xor(ss,mk); }
      float mean=s*(1.f/128.f), var=ss*(1.f/128.f)-mean*mean, inv=rsqrtf(fmaxf(var,0.f)+1e-5f);
      float s2=0.f, ss2=0.f; float yv[8];
      #pragma unroll
      for (int ni=0;ni<8;ni++){
        int n = ni*16+lr;
        float y = (xv[ni]-mean)*inv*gcng[n] + gcnb[n];
        yv[ni]=y; s2+=y; ss2+=y*y;
        XG[(size_t)m*128+n] = f2bf(y);
        acc[mi][ni][r] = y;
      }
      #pragma unroll
      for (int mk=1;mk<16;mk<<=1){ s2 += __shfl_xor(s2,mk); ss2 += __shfl_xor(ss2,mk); }
      float mean2=s2*(1.f/128.f), var2=ss2*(1.f/128.f)-mean2*mean2, inv2=rsqrtf(fmaxf(var2,0.f)+1e-5f);
      #pragma unroll
      for (int ni=0;ni<8;ni++){
        int n = ni*16+lr;
        float t1 = (yv[ni]-mean2)*inv2*ln1g[n] + ln1b[n];
        As[ml*128 + (((n>>3)^(ml&7))*8) + (n&7)] = f2bf(t1);
      }
    }
  }
  __syncthreads();
  f32x4 acc2[2][8] = {};
  #pragma unroll
  for (int kk=0;kk<128;kk+=32){
    const int c = (kk>>3) + lh;
    short8 af[2], bfr[8];
    #pragma unroll
    for (int mi=0;mi<2;mi++){ int row=wm+mi*16+lr; af[mi]  = *(const short8*)&As[row*128 + ((c^(row&7))*8)]; }
    #pragma unroll
    for (int ni=0;ni<8;ni++){ int row=ni*16+lr;    bfr[ni] = *(const short8*)&Ws[row*128 + ((c^(row&7))*8)]; }
    #pragma unroll
    for (int mi=0;mi<2;mi++)
      #pragma unroll
      for (int ni=0;ni<8;ni++)
        acc2[mi][ni] = __builtin_amdgcn_mfma_f32_16x16x32_bf16(af[mi], bfr[ni], acc2[mi][ni], 0,0,0);
  }
  #pragma unroll
  for (int mi=0;mi<2;mi++){
    #pragma unroll
    for (int r=0;r<4;r++){
      const int m = m0 + wm + mi*16 + lh*4 + r;
      float hv[8]; float s=0.f, ss=0.f;
      #pragma unroll
      for (int ni=0;ni<8;ni++){
        int n = ni*16+lr;
        float h = acc2[mi][ni][r] + Ben[n] + acc[mi][ni][r];
        hv[ni]=h; s+=h; ss+=h*h;
      }
      #pragma unroll
      for (int mk=1;mk<16;mk<<=1){ s += __shfl_xor(s,mk); ss += __shfl_xor(ss,mk); }
      float mean=s*(1.f/128.f), var=ss*(1.f/128.f)-mean*mean, inv=rsqrtf(fmaxf(var,0.f)+1e-5f);
      #pragma unroll
      for (int ni=0;ni<8;ni++){
        int n = ni*16+lr;
        T2[(size_t)m*128+n] = f2bf((hv[ni]-mean)*inv*ln2g[n] + ln2b[n]);
        P [(size_t)m*128+n] = f2bf(acc[mi][ni][r] + hv[ni]);
      }
    }
  }
}

// ---------------------------------------------------------------------------
// Fused FFN v2: S = P + relu(T2 @ W1 + b1) @ W2 + b2
// 256 rows/block, 8 waves x 32 rows. T2 (A-operand) lives in REGISTERS
// (chunk-invariant, loaded once from global) -> no As LDS buffer at all.
// LDS = W1s 16K + W2s 16K + Hs 32K = 64KB -> 2 blocks/CU. Weight regs
// prefetch (T14). GEMM1 C[n1][m]; pack -> Hs swizzled; GEMM2 64x64/wave.
// ---------------------------------------------------------------------------
__global__ __launch_bounds__(512,4) void ffn_k(
    const ushort* __restrict__ T2, const ushort* __restrict__ W1t, const float* __restrict__ b1,
    const ushort* __restrict__ W2t, const float* __restrict__ b2,
    const ushort* __restrict__ P,
    ushort* __restrict__ S)
{
  __shared__ __align__(16) ushort W1s[64*128];  // 16KB
  __shared__ __align__(16) ushort W2s[128*64];  // 16KB
  __shared__ __align__(16) ushort Hs [256*64];  // 32KB
  const int t = threadIdx.x;
  const int m0 = blockIdx.x*256;
  const int w=t>>6, lane=t&63, lr=lane&15, lh=lane>>4;
  const int wb = w*32;                     // GEMM1: 32 rows per wave
  const int wm2=(w>>1)*64, wn2=(w&1)*64;   // GEMM2: 64x64 per wave
  // ---- T2 rows -> registers (chunk-invariant A-operand) ----
  short8 af[2][4];
  #pragma unroll
  for (int mi=0;mi<2;mi++)
    #pragma unroll
    for (int kki=0;kki<4;kki++)
      af[mi][kki] = *(const short8*)(T2 + (size_t)(m0+wb+mi*16+lr)*128 + kki*32 + lh*8);
  // ---- weight staging offsets + first prefetch ----
  const int f0=t, f1=512+t;
  const int r10=f0>>4, c10=f0&15, r11=f1>>4, c11=f1&15;
  const int r20=f0>>3, c20=f0&7,  r21=f1>>3, c21=f1&7;
  const size_t w1o0 = (size_t)r10*128 + ((c10^(r10&7))*8);
  const size_t w1o1 = (size_t)r11*128 + ((c11^(r11&7))*8);
  const size_t w2o0 = (size_t)r20*2048 + ((c20^(r20&7))*8);
  const size_t w2o1 = (size_t)r21*2048 + ((c21^(r21&7))*8);
  uint4 w1r0 = *(const uint4*)(W1t + w1o0);
  uint4 w1r1 = *(const uint4*)(W1t + w1o1);
  uint4 w2r0 = *(const uint4*)(W2t + w2o0);
  uint4 w2r1 = *(const uint4*)(W2t + w2o1);
  f32x4 acc2[4][4] = {};
  const unsigned int msw = (unsigned int)((lr&7)<<4);
  for (int ch=0; ch<32; ++ch){
    __syncthreads();                       // prev-chunk readers done
    *(uint4*)&W1s[f0*8] = w1r0;
    *(uint4*)&W1s[f1*8] = w1r1;
    *(uint4*)&W2s[f0*8] = w2r0;
    *(uint4*)&W2s[f1*8] = w2r1;
    if (ch < 31){
      const size_t b1o = (size_t)(ch+1)*8192;
      const size_t b2o = (size_t)(ch+1)*64;
      w1r0 = *(const uint4*)(W1t + b1o + w1o0);
      w1r1 = *(const uint4*)(W1t + b1o + w1o1);
      w2r0 = *(const uint4*)(W2t + b2o + w2o0);
      w2r1 = *(const uint4*)(W2t + b2o + w2o1);
    }
    __syncthreads();                       // staged weights visible
    // GEMM1: C[n1][m], 64 n1 x 32 m per wave
    f32x4 a1[2][4] = {};
    #pragma unroll
    for (int kki=0;kki<4;kki++){
      const int c = kki*4 + lh;
      short8 wf[4];
      #pragma unroll
      for (int ni=0;ni<4;ni++){
        int nr = ni*16 + lr;
        wf[ni] = *(const short8*)&W1s[nr*128 + ((c^(nr&7))*8)];
      }
      #pragma unroll
      for (int mi=0;mi<2;mi++)
        #pragma unroll
        for (int ni=0;ni<4;ni++)
          a1[mi][ni] = __builtin_amdgcn_mfma_f32_16x16x32_bf16(wf[ni], af[mi][kki], a1[mi][ni],0,0,0);
    }
    // bias+relu+pack -> Hs (wave's 32 rows, swizzled)
    #pragma unroll
    for (int mi=0;mi<2;mi++){
      const int mwi = wb + mi*16 + lr;
      #pragma unroll
      for (int ni=0;ni<4;ni++){
        float v0 = fmaxf(a1[mi][ni][0] + b1[ch*64 + ni*16 + lh*4 + 0], 0.f);
        float v1 = fmaxf(a1[mi][ni][1] + b1[ch*64 + ni*16 + lh*4 + 1], 0.f);
        float v2 = fmaxf(a1[mi][ni][2] + b1[ch*64 + ni*16 + lh*4 + 2], 0.f);
        float v3 = fmaxf(a1[mi][ni][3] + b1[ch*64 + ni*16 + lh*4 + 3], 0.f);
        uint2 p;
        p.x = f2bf2(v0, v1);
        p.y = f2bf2(v2, v3);
        *(uint2*)((char*)Hs + mwi*128 + (((unsigned int)(ni*32 + lh*8)) ^ msw)) = p;
      }
    }
    __syncthreads();                       // Hs visible cross-wave
    // GEMM2: 64m x 64n per wave, K=64
    #pragma unroll
    for (int kk=0;kk<64;kk+=32){
      const int c = (kk>>3) + lh;
      short8 af2[4], bf2r[4];
      #pragma unroll
      for (int mi=0;mi<4;mi++){
        int mr = wm2 + mi*16 + lr;
        af2[mi] = *(const short8*)((const char*)Hs + mr*128 + (((unsigned int)(c*16)) ^ ((unsigned int)((mr&7)<<4))));
      }
      #pragma unroll
      for (int ni=0;ni<4;ni++){
        int nr = wn2 + ni*16 + lr;
        bf2r[ni] = *(const short8*)&W2s[nr*64 + ((c^(nr&7))*8)];
      }
      #pragma unroll
      for (int mi=0;mi<4;mi++)
        #pragma unroll
        for (int ni=0;ni<4;ni++)
          acc2[mi][ni] = __builtin_amdgcn_mfma_f32_16x16x32_bf16(af2[mi], bf2r[ni], acc2[mi][ni],0,0,0);
    }
  }
  #pragma unroll
  for (int mi=0;mi<4;mi++)
    #pragma unroll
    for (int ni=0;ni<4;ni++)
      #pragma unroll
      for (int r=0;r<4;r++){
        int m = m0 + wm2 + mi*16 + lh*4 + r;
        int n = wn2 + ni*16 + lr;
        float v = acc2[mi][ni][r] + b2[n] + bf2f(P[(size_t)m*128+n]);
        S[(size_t)m*128+n] = f2bf(v);
      }
}

// ---------------------------------------------------------------------------
// group-LN(128) then add Gc then global-LN(1024); wave per row
// ---------------------------------------------------------------------------
__global__ void ln_cg_k(const ushort* __restrict__ S, const ushort* __restrict__ Gc,
    const float* __restrict__ gsg, const float* __restrict__ gsb,
    const float* __restrict__ glg, const float* __restrict__ glb,
    ushort* __restrict__ O, int nrows)
{
  int gw = (int)((blockIdx.x*blockDim.x + threadIdx.x)>>6);
  int lane = threadIdx.x & 63;
  int nw = (int)((gridDim.x*blockDim.x)>>6);
  for (int row=gw; row<nrows; row+=nw){
    size_t base = (size_t)row*1024 + (size_t)lane*16;
    float x[16];
    short8 v0 = *(const short8*)(S+base);
    short8 v1 = *(const short8*)(S+base+8);
    #pragma unroll
    for (int i=0;i<8;i++){ x[i]=bf2f((ushort)v0[i]); x[8+i]=bf2f((ushort)v1[i]); }
    float s=0, ss=0;
    #pragma unroll
    for (int i=0;i<16;i++){ s+=x[i]; ss+=x[i]*x[i]; }
    #pragma unroll
    for (int mk=1;mk<8;mk<<=1){ s+=__shfl_xor(s,mk); ss+=__shfl_xor(ss,mk); }
    float mean=s*(1.f/128.f), var=ss*(1.f/128.f)-mean*mean, inv=rsqrtf(fmaxf(var,0.f)+1e-5f);
    int j0=(lane&7)*16;
    short8 gc0 = *(const short8*)(Gc+base);
    short8 gc1 = *(const short8*)(Gc+base+8);
    float z[16];
    #pragma unroll
    for (int i=0;i<16;i++){
      float y = (x[i]-mean)*inv*gsg[j0+i] + gsb[j0+i];
      z[i] = y + bf2f((ushort)(i<8? gc0[i] : gc1[i-8]));
    }
    s=0; ss=0;
    #pragma unroll
    for (int i=0;i<16;i++){ s+=z[i]; ss+=z[i]*z[i]; }
    #pragma unroll
    for (int mk=1;mk<64;mk<<=1){ s+=__shfl_xor(s,mk); ss+=__shfl_xor(ss,mk); }
    mean = s*(1.f/1024.f); var = ss*(1.f/1024.f)-mean*mean; inv = rsqrtf(fmaxf(var,0.f)+1e-5f);
    int d0 = lane*16;
    float rr[16];
    #pragma unroll
    for (int i=0;i<16;i++) rr[i] = (z[i]-mean)*inv*glg[d0+i] + glb[d0+i];
    uint4 oa, ob;
    oa.x=f2bf2(rr[0],rr[1]);  oa.y=f2bf2(rr[2],rr[3]);
    oa.z=f2bf2(rr[4],rr[5]);  oa.w=f2bf2(rr[6],rr[7]);
    ob.x=f2bf2(rr[8],rr[9]);  ob.y=f2bf2(rr[10],rr[11]);
    ob.z=f2bf2(rr[12],rr[13]);ob.w=f2bf2(rr[14],rr[15]);
    *(uint4*)(O+base)   = oa;
    *(uint4*)(O+base+8) = ob;
  }
}

// ---------------------------------------------------------------------------
// Prep kernels
// ---------------------------------------------------------------------------
__global__ void freq_k(float* fr){
  int i = threadIdx.x;
  if (i < 512) fr[i] = expf((-9.210340371976184f/511.f) * (float)i);
}

__global__ void temb_k(const float* __restrict__ tt, const float* __restrict__ fr,
                       ushort* __restrict__ te){
  int idx = blockIdx.x*blockDim.x + threadIdx.x;
  int stride = gridDim.x*blockDim.x;
  for (; idx < 16384*512; idx += stride){
    int b = idx>>9, i = idx&511;
    float ang = tt[b]*fr[i];
    te[(size_t)b*1024 + i]       = f2bf(sinf(ang));
    te[(size_t)b*1024 + 512 + i] = f2bf(cosf(ang));
  }
}

__global__ void cvt_k(const float* __restrict__ in, ushort* __restrict__ out, size_t n4){
  size_t i = (size_t)blockIdx.x*blockDim.x + threadIdx.x;
  size_t st = (size_t)gridDim.x*blockDim.x;
  for (; i<n4; i+=st){
    const float4 v = ((const float4*)in)[i];
    uint2 o; o.x = f2bf2(v.x, v.y); o.y = f2bf2(v.z, v.w);
    ((uint2*)out)[i] = o;
  }
}

// transpose+convert: in [bz][R][C] f32 -> out [bz][C][R] bf16
__global__ void tcvt_k(const float* __restrict__ in, ushort* __restrict__ out,
                       int R, int C, long in_bs, long out_bs){
  __shared__ float tile[32][33];
  const int bz = blockIdx.z;
  const int r0 = blockIdx.y*32, c0 = blockIdx.x*32;
  const int tx = threadIdx.x & 31, ty = threadIdx.x >> 5;
  const float* ip = in + (size_t)bz*in_bs;
  ushort* op = out + (size_t)bz*out_bs;
  #pragma unroll
  for (int i=0;i<32;i+=8) tile[ty+i][tx] = ip[(size_t)(r0+ty+i)*C + c0+tx];
  __syncthreads();
  #pragma unroll
  for (int i=0;i<32;i+=8) op[(size_t)(c0+ty+i)*R + r0+tx] = f2bf(tile[tx][ty+i]);
}

// parallel Wv@Wo collapse: grid (12, 128) -> (pair, k-row); 128 threads = n
__global__ __launch_bounds__(128) void comb_small_k(
     const float* __restrict__ wvA, const float* __restrict__ woA,
     const float* __restrict__ bvA, const float* __restrict__ boA,
     const float* __restrict__ wvB, const float* __restrict__ woB,
     const float* __restrict__ bvB, const float* __restrict__ boB,
     ushort* __restrict__ voA, float* __restrict__ cbA,
     ushort* __restrict__ voB, float* __restrict__ cbB)
{
  const int pair = blockIdx.x;
  const int l = pair >> 1, which = pair & 1;
  const int k = blockIdx.y;
  const int n = threadIdx.x;
  const float* wv = (which? wvB:wvA) + (size_t)l*16384;
  const float* wo = (which? woB:woA) + (size_t)l*16384;
  ushort* vo = (which? voB:voA) + (size_t)l*16384;
  float acc = 0.f;
  #pragma unroll 8
  for (int j=0;j<128;j++) acc += wv[k*128+j]*wo[j*128+n];
  vo[(size_t)n*128 + k] = f2bf(acc);
  if (k == 0){
    const float* bv = (which? bvB:bvA) + l*128;
    const float* bo = (which? boB:boA) + l*128;
    float a2 = 0.f;
    #pragma unroll 8
    for (int kk=0;kk<128;kk++) a2 += bv[kk]*wo[kk*128+n];
    float* cb = (which? cbB:cbA) + l*128;
    cb[n] = a2 + bo[n];
  }
}

// cb[l][n] = sum_k bv[l][k]*wo[l][k][n] + bo[l][n]
__global__ __launch_bounds__(256) void glob_bias_k(
    const float* __restrict__ bv, const float* __restrict__ wo,
    const float* __restrict__ bo, float* __restrict__ cb){
  __shared__ float red[256];
  const int l = blockIdx.y;
  const int nl = threadIdx.x & 63;
  const int ks = threadIdx.x >> 6;
  const int n = blockIdx.x*64 + nl;
  const float* wol = wo + (size_t)l*1048576;
  float acc = 0.f;
  for (int k=ks*256; k<ks*256+256; ++k) acc += bv[l*1024+k]*wol[(size_t)k*1024+n];
  red[threadIdx.x] = acc;
  __syncthreads();
  if (ks == 0){
    float v = red[nl] + red[nl+64] + red[nl+128] + red[nl+192];
    cb[l*1024+n] = v + bo[l*1024+n];
  }
}

// ---------------------------------------------------------------------------
extern "C" void kernel_launch(void* const* d_in, const int* in_sizes, int n_in,
                              void* d_out, int out_size, void* d_ws, size_t ws_size,
                              hipStream_t stream)
{
  const float* x    = (const float*)d_in[0];
  const float* tt   = (const float*)d_in[1];
  const int*   uid  = (const int*)d_in[2];
  const int*   scr  = (const int*)d_in[3];
  const float* utab = (const float*)d_in[4];
  const float* stab = (const float*)d_in[5];
  const float* tp_w1=(const float*)d_in[6];
  const float* tp_b1=(const float*)d_in[7];
  const float* tp_w2=(const float*)d_in[8];
  const float* tp_b2=(const float*)d_in[9];
  const float* gp_w =(const float*)d_in[10];
  const float* gp_b =(const float*)d_in[11];
  const float* gca_wv=(const float*)d_in[14];
  const float* gca_wo=(const float*)d_in[15];
  const float* gca_bv=(const float*)d_in[18];
  const float* gca_bo=(const float*)d_in[19];
  const float* enc_wv=(const float*)d_in[22];
  const float* enc_wo=(const float*)d_in[23];
  const float* enc_bv=(const float*)d_in[26];
  const float* enc_bo=(const float*)d_in[27];
  const float* glob_wv=(const float*)d_in[30];
  const float* glob_wo=(const float*)d_in[31];
  const float* glob_bv=(const float*)d_in[34];
  const float* glob_bo=(const float*)d_in[35];
  const float* ln1_g=(const float*)d_in[36];
  const float* ln1_b=(const float*)d_in[37];
  const float* ln2_g=(const float*)d_in[38];
  const float* ln2_b=(const float*)d_in[39];
  const float* gcn_g=(const float*)d_in[40];
  const float* gcn_b=(const float*)d_in[41];
  const float* gsn_g=(const float*)d_in[42];
  const float* gsn_b=(const float*)d_in[43];
  const float* gln_g=(const float*)d_in[44];
  const float* gln_b=(const float*)d_in[45];
  const float* ff_w1=(const float*)d_in[46];
  const float* ff_b1=(const float*)d_in[47];
  const float* ff_w2=(const float*)d_in[48];
  const float* ff_b2=(const float*)d_in[49];
  const float* op_w1=(const float*)d_in[50];
  const float* op_b1=(const float*)d_in[51];
  const float* op_w2=(const float*)d_in[52];
  const float* op_b2=(const float*)d_in[53];

  char* ws = (char*)d_ws;
  size_t off = 0;
  auto alloc = [&](size_t bytes)->char*{ char* p = ws+off; off += (bytes+255)&~(size_t)255; return p; };

  // ---- persistent region ----
  ushort* W_gt   = (ushort*)alloc(1024UL*1024*2);
  ushort* W_ff1t = (ushort*)alloc(6UL*2048*128*2);
  ushort* W_ff2t = (ushort*)alloc(6UL*128*2048*2);
  ushort* W_gvo  = (ushort*)alloc(6UL*1024*1024*2);
  ushort* W_cvo  = (ushort*)alloc(6UL*128*128*2);
  ushort* W_evo  = (ushort*)alloc(6UL*128*128*2);
  float*  B_cca  = (float*)alloc(6UL*128*4);
  float*  B_cen  = (float*)alloc(6UL*128*4);
  float*  B_cgl  = (float*)alloc(6UL*1024*4);
  float*  F_freq = (float*)alloc(512*4);
  ushort* A_cond = (ushort*)alloc(16384UL*1024*2);
  ushort* A_cg   = (ushort*)alloc(16384UL*1024*2);
  ushort* A_xg   = (ushort*)alloc(16384UL*1024*2);
  ushort* S0 = (ushort*)alloc(16384UL*1024*2);
  ushort* S1 = (ushort*)alloc(16384UL*1024*2);
  ushort* SD = (ushort*)d_out;
  (void)ws_size; (void)in_sizes; (void)n_in; (void)out_size;

  // aliases
  ushort* A_te   = S0;
  ushort* W_tp1t = S1;
  ushort* W_tp2t = S1 + 4194304;
  ushort* H1     = SD;                 // 64 MB: 8192 x 4096 bf16
  ushort* A_xbf  = S0;
  ushort* W_gwot = S1;
  ushort* W_gwv  = S1 + 6291456;
  ushort* W_op1t = W_gvo;
  ushort* W_op2t = W_gvo + 2097152;
  ushort* O1     = S0;                 // 64 MB spanning S0+S1

  // ---- phase 1: time embedding + MLP (2 chunks of 8192 rows) ----
  hipLaunchKernelGGL(freq_k, dim3(1), dim3(512), 0, stream, F_freq);
  hipLaunchKernelGGL(temb_k, dim3(4096), dim3(256), 0, stream, tt, F_freq, A_te);
  hipLaunchKernelGGL(tcvt_k, dim3(128,32,1), dim3(256), 0, stream, tp_w1, W_tp1t, 1024, 4096, 0L, 0L);
  hipLaunchKernelGGL(tcvt_k, dim3(32,128,1), dim3(256), 0, stream, tp_w2, W_tp2t, 4096, 1024, 0L, 0L);
  for (int c=0;c<2;c++){
    hipLaunchKernelGGL((gemm_k<EPI_GELU,false>), dim3(32,64), dim3(256), 0, stream,
        A_te + (size_t)c*8192*1024, W_tp1t, (void*)H1, tp_b1,
        (const ushort*)nullptr,(const int*)nullptr,(const int*)nullptr,
        (const float*)nullptr,(const float*)nullptr, 8192,4096,1024,4096, 0L,0L,0L);
    hipLaunchKernelGGL((gemm_k<EPI_COND,false>), dim3(8,64), dim3(256), 0, stream,
        H1, W_tp2t, (void*)(A_cond + (size_t)c*8192*1024), tp_b2,
        (const ushort*)nullptr, uid + c*8192, scr + c*8192, utab, stab,
        8192,1024,4096,1024, 0L,0L,0L);
  }

  // ---- phase 2: group projections of x and cond ----
  hipLaunchKernelGGL(tcvt_k, dim3(4,32,8), dim3(256), 0, stream, gp_w, W_gt, 1024, 128, (long)(1024*128), (long)(128*1024));
  hipLaunchKernelGGL(cvt_k, dim3(4096), dim3(256), 0, stream, x, A_xbf, (size_t)(16384UL*1024/4));
  hipLaunchKernelGGL((gemm_k<EPI_NONE,false>), dim3(8,128), dim3(256), 0, stream,
      A_xbf, W_gt, (void*)A_xg, gp_b, (const ushort*)nullptr,(const int*)nullptr,(const int*)nullptr,
      (const float*)nullptr,(const float*)nullptr, 16384,1024,1024,1024, 0L,0L,0L);
  hipLaunchKernelGGL((gemm_k<EPI_NONE,false>), dim3(8,128), dim3(256), 0, stream,
      A_cond, W_gt, (void*)A_cg, gp_b, (const ushort*)nullptr,(const int*)nullptr,(const int*)nullptr,
      (const float*)nullptr,(const float*)nullptr, 16384,1024,1024,1024, 0L,0L,0L);

  // ---- phase 3: collapsed attention weights ----
  hipLaunchKernelGGL(tcvt_k, dim3(32,32,6), dim3(256), 0, stream, glob_wo, W_gwot, 1024, 1024, (long)(1024*1024), (long)(1024*1024));
  hipLaunchKernelGGL(cvt_k, dim3(2048), dim3(256), 0, stream, glob_wv, W_gwv, (size_t)(6UL*1024*1024/4));
  hipLaunchKernelGGL((gemm_k<EPI_NONE,false>), dim3(8,8,6), dim3(256), 0, stream,
      W_gwot, W_gwv, (void*)W_gvo,
      (const float*)nullptr, (const ushort*)nullptr, (const int*)nullptr, (const int*)nullptr,
      (const float*)nullptr, (const float*)nullptr, 1024,1024,1024,1024,
      1048576L,1048576L,1048576L);
  hipLaunchKernelGGL(comb_small_k, dim3(12,128), dim3(128), 0, stream,
      gca_wv, gca_wo, gca_bv, gca_bo, enc_wv, enc_wo, enc_bv, enc_bo,
      W_cvo, B_cca, W_evo, B_cen);
  hipLaunchKernelGGL(glob_bias_k, dim3(16,6), dim3(256), 0, stream, glob_bv, glob_wo, glob_bo, B_cgl);
  hipLaunchKernelGGL(tcvt_k, dim3(64,4,6), dim3(256), 0, stream, ff_w1, W_ff1t, 128, 2048, (long)(128*2048), (long)(2048*128));
  hipLaunchKernelGGL(tcvt_k, dim3(4,64,6), dim3(256), 0, stream, ff_w2, W_ff2t, 2048, 128, (long)(2048*128), (long)(128*2048));

  // ---- layer loop ----
  for (int l=0;l<6;l++){
    ushort* T2 = S0; ushort* SS = S1; ushort* XGL = S0;
    ushort* P  = SD;
    ushort* GC = SD + 16777216;
    hipLaunchKernelGGL(enc_fused_k, dim3(1024), dim3(256), 0, stream,
      A_cg, W_cvo + (size_t)l*16384, B_cca + l*128,
      W_evo + (size_t)l*16384, B_cen + l*128,
      A_xg,
      gcn_g+l*128, gcn_b+l*128, ln1_g+l*128, ln1_b+l*128, ln2_g+l*128, ln2_b+l*128,
      P, T2);
    hipLaunchKernelGGL(ffn_k, dim3(512), dim3(512), 0, stream,
      T2, W_ff1t + (size_t)l*262144, ff_b1 + l*2048, W_ff2t + (size_t)l*262144, ff_b2 + l*128,
      P, SS);
    hipLaunchKernelGGL((gemm_k<EPI_NONE,false>), dim3(8,128), dim3(256), 0, stream,
      A_cond, W_gvo + (size_t)l*1048576, (void*)GC, B_cgl + l*1024,
      (const ushort*)nullptr,(const int*)nullptr,(const int*)nullptr,(const float*)nullptr,(const float*)nullptr,
      16384,1024,1024,1024, 0L,0L,0L);
    hipLaunchKernelGGL(ln_cg_k, dim3(512), dim3(256), 0, stream,
      SS, GC, gsn_g+l*128, gsn_b+l*128, gln_g+l*1024, gln_b+l*1024, XGL, 16384);
    hipLaunchKernelGGL((gemm_k<EPI_NONE,false>), dim3(8,128), dim3(256), 0, stream,
      XGL, W_gt, (void*)A_xg, gp_b,
      (const ushort*)nullptr,(const int*)nullptr,(const int*)nullptr,(const float*)nullptr,(const float*)nullptr,
      16384,1024,1024,1024, 0L,0L,0L);
  }

  // ---- output MLP ----
  hipLaunchKernelGGL(tcvt_k, dim3(64,32,1), dim3(256), 0, stream, op_w1, W_op1t, 1024, 2048, 0L, 0L);
  hipLaunchKernelGGL(tcvt_k, dim3(32,64,1), dim3(256), 0, stream, op_w2, W_op2t, 2048, 1024, 0L, 0L);
  hipLaunchKernelGGL((gemm_k<EPI_GELU,false>), dim3(16,128), dim3(256), 0, stream,
      A_xg, W_op1t, (void*)O1, op_b1,
      (const ushort*)nullptr,(const int*)nullptr,(const int*)nullptr,(const float*)nullptr,(const float*)nullptr,
      16384,2048,1024,2048, 0L,0L,0L);
  hipLaunchKernelGGL((gemm_k<EPI_NONE,true>), dim3(8,128), dim3(256), 0, stream,
      O1, W_op2t, d_out, op_b2,
      (const ushort*)nullptr,(const int*)nullptr,(const int*)nullptr,(const float*)nullptr,(const float*)nullptr,
      16384,1024,2048,1024, 0L,0L,0L);
}

// Round 11
// 2564.255 us; speedup vs baseline: 2.0829x; 2.0829x over previous
//
#include <hip/hip_runtime.h>
#include <hip/hip_bf16.h>
#include <cstdint>

#define DEV __device__ __forceinline__

typedef __attribute__((ext_vector_type(8))) short short8;
typedef __attribute__((ext_vector_type(4))) short short4v;
typedef __attribute__((ext_vector_type(4))) float f32x4;

DEV float bf2f(ushort u){ union{ unsigned int i; float f;} c; c.i = ((unsigned int)u)<<16; return c.f; }
DEV ushort f2bf(float f){
  unsigned int r;
  asm("v_cvt_pk_bf16_f32 %0, %1, %1" : "=v"(r) : "v"(f));
  return (ushort)r;
}
DEV unsigned int f2bf2(float lo, float hi){
  unsigned int r;
  asm("v_cvt_pk_bf16_f32 %0, %1, %2" : "=v"(r) : "v"(lo), "v"(hi));
  return r;
}
// branch-free gelu: A&S 7.1.26 erf approx, |err|<=1.5e-7
DEV float gelu_f(float v){
  float a = fabsf(v)*0.7071067811865476f;
  float t = __builtin_amdgcn_rcpf(fmaf(0.3275911f, a, 1.f));
  float p = t*(0.254829592f + t*(-0.284496736f + t*(1.421413741f + t*(-1.453152027f + t*1.061405429f))));
  float e = __expf(-a*a);
  float er = fmaf(-p, e, 1.f);
  float sgn = (v < 0.f) ? -er : er;
  return 0.5f*v*(1.f+sgn);
}

DEV void gld_lds16(const void* g, void* l){
  __builtin_amdgcn_global_load_lds(
      (const __attribute__((address_space(1))) unsigned int*)g,
      (__attribute__((address_space(3))) unsigned int*)l, 16, 0, 0);
}

// ---------------------------------------------------------------------------
// Generic bf16 MFMA GEMM (optionally batched over blockIdx.z):
// C[M,N] = epi(A[M,K] @ W^T[N,K] + bias ...). 128x128 tile, BK=64.
// T2 chunk16 XOR swizzle on LDS; T1 XCD-aware block swizzle.
// ---------------------------------------------------------------------------
enum { EPI_NONE=0, EPI_GELU=1, EPI_COND=2, EPI_RESID=3 };

template<int EPI, bool OUTF32>
__global__ __launch_bounds__(256,2) void gemm_k(
    const ushort* __restrict__ A, const ushort* __restrict__ Wt,
    void* __restrict__ Cp, const float* __restrict__ bias,
    const ushort* __restrict__ resid,
    const int* __restrict__ uid, const int* __restrict__ scr,
    const float* __restrict__ utab, const float* __restrict__ stab,
    int M, int N, int K, int ldc, long a_bs, long w_bs, long c_bs)
{
  __shared__ __align__(16) ushort As[128*64];
  __shared__ __align__(16) ushort Ws[128*64];
  A  += (size_t)blockIdx.z * a_bs;
  Wt += (size_t)blockIdx.z * w_bs;
  ushort* Cb = (ushort*)Cp + (size_t)blockIdx.z * c_bs;
  const int flat = blockIdx.y*gridDim.x + blockIdx.x;
  const int nwg  = gridDim.x*gridDim.y;
  const int swz  = (flat & 7)*(nwg >> 3) + (flat >> 3);
  const int n0 = (swz % gridDim.x)*128, m0 = (swz / gridDim.x)*128;
  const int t = threadIdx.x;
  const int w = t>>6, lane=t&63, lr=lane&15, lh=lane>>4;
  const int wm=(w>>1)*64, wn=(w&1)*64;
  f32x4 acc[4][4] = {};
  for (int k0=0;k0<K;k0+=64){
    #pragma unroll
    for (int i=0;i<4;i++){
      int f=i*256+t; int r=f>>3, c=f&7;
      gld_lds16(A + (size_t)(m0+r)*K + k0 + ((c^(r&7))*8), &As[f*8]);
    }
    #pragma unroll
    for (int i=0;i<4;i++){
      int f=i*256+t; int r=f>>3, c=f&7;
      gld_lds16(Wt + (size_t)(n0+r)*K + k0 + ((c^(r&7))*8), &Ws[f*8]);
    }
    __syncthreads();
    #pragma unroll
    for (int kk=0;kk<64;kk+=32){
      const int c = (kk>>3) + lh;
      short8 af[4], bfr[4];
      #pragma unroll
      for (int mi=0;mi<4;mi++){ int row=wm+mi*16+lr; af[mi]  = *(const short8*)&As[row*64 + ((c^(row&7))*8)]; }
      #pragma unroll
      for (int ni=0;ni<4;ni++){ int row=wn+ni*16+lr; bfr[ni] = *(const short8*)&Ws[row*64 + ((c^(row&7))*8)]; }
      #pragma unroll
      for (int mi=0;mi<4;mi++)
        #pragma unroll
        for (int ni=0;ni<4;ni++)
          acc[mi][ni] = __builtin_amdgcn_mfma_f32_16x16x32_bf16(af[mi], bfr[ni], acc[mi][ni], 0,0,0);
    }
    __syncthreads();
  }
  #pragma unroll
  for (int mi=0;mi<4;mi++){
    #pragma unroll
    for (int ni=0;ni<4;ni++){
      #pragma unroll
      for (int r=0;r<4;r++){
        int m = m0 + wm + mi*16 + lh*4 + r;
        int n = n0 + wn + ni*16 + lr;
        float v = acc[mi][ni][r];
        if (bias) v += bias[n];
        if (EPI==EPI_GELU) v = gelu_f(v);
        if (EPI==EPI_COND) v += utab[(size_t)uid[m]*1024 + n] + stab[(size_t)scr[m]*1024 + n];
        if (EPI==EPI_RESID) v += bf2f(resid[(size_t)m*ldc + n]);
        if (OUTF32) ((float*)Cp)[(size_t)m*ldc + n] = v;
        else        Cb[(size_t)m*ldc + n] = f2bf(v);
      }
    }
  }
}

// ---------------------------------------------------------------------------
// Fused encoder front-half, per 128-row tile (N=K=128 throughout).
// ---------------------------------------------------------------------------
__global__ __launch_bounds__(256,2) void enc_fused_k(
    const ushort* __restrict__ CG, const ushort* __restrict__ Wca, const float* __restrict__ Bca,
    const ushort* __restrict__ Wen, const float* __restrict__ Ben,
    ushort* __restrict__ XG,
    const float* __restrict__ gcng, const float* __restrict__ gcnb,
    const float* __restrict__ ln1g, const float* __restrict__ ln1b,
    const float* __restrict__ ln2g, const float* __restrict__ ln2b,
    ushort* __restrict__ P, ushort* __restrict__ T2)
{
  __shared__ __align__(16) ushort As[128*128]; // CG tile, then T1
  __shared__ __align__(16) ushort Ws[128*128]; // Wca, then Wen
  const int t = threadIdx.x;
  const int m0 = blockIdx.x*128;
  const int w = t>>6, lane=t&63, lr=lane&15, lh=lane>>4;
  const int wm = w*32;
  #pragma unroll
  for (int i=0;i<8;i++){
    int f=i*256+t; int r=f>>4, c=f&15;
    gld_lds16(CG + (size_t)(m0+r)*128 + ((c^(r&7))*8), &As[f*8]);
  }
  #pragma unroll
  for (int i=0;i<8;i++){
    int f=i*256+t; int r=f>>4, c=f&15;
    gld_lds16(Wca + (size_t)r*128 + ((c^(r&7))*8), &Ws[f*8]);
  }
  __syncthreads();
  f32x4 acc[2][8] = {};
  #pragma unroll
  for (int kk=0;kk<128;kk+=32){
    const int c = (kk>>3) + lh;
    short8 af[2], bfr[8];
    #pragma unroll
    for (int mi=0;mi<2;mi++){ int row=wm+mi*16+lr; af[mi]  = *(const short8*)&As[row*128 + ((c^(row&7))*8)]; }
    #pragma unroll
    for (int ni=0;ni<8;ni++){ int row=ni*16+lr;    bfr[ni] = *(const short8*)&Ws[row*128 + ((c^(row&7))*8)]; }
    #pragma unroll
    for (int mi=0;mi<2;mi++)
      #pragma unroll
      for (int ni=0;ni<8;ni++)
        acc[mi][ni] = __builtin_amdgcn_mfma_f32_16x16x32_bf16(af[mi], bfr[ni], acc[mi][ni], 0,0,0);
  }
  __syncthreads();
  #pragma unroll
  for (int i=0;i<8;i++){
    int f=i*256+t; int r=f>>4, c=f&15;
    gld_lds16(Wen + (size_t)r*128 + ((c^(r&7))*8), &Ws[f*8]);
  }
  #pragma unroll
  for (int mi=0;mi<2;mi++){
    #pragma unroll
    for (int r=0;r<4;r++){
      const int ml = wm + mi*16 + lh*4 + r;
      const int m  = m0 + ml;
      float xv[8]; float s=0.f, ss=0.f;
      #pragma unroll
      for (int ni=0;ni<8;ni++){
        int n = ni*16+lr;
        float v = acc[mi][ni][r] + Bca[n] + bf2f(XG[(size_t)m*128+n]);
        xv[ni]=v; s+=v; ss+=v*v;
      }
      #pragma unroll
      for (int mk=1;mk<16;mk<<=1){ s += __shfl_xor(s,mk); ss += __shfl_xor(ss,mk); }
      float mean=s*(1.f/128.f), var=ss*(1.f/128.f)-mean*mean, inv=rsqrtf(fmaxf(var,0.f)+1e-5f);
      float s2=0.f, ss2=0.f; float yv[8];
      #pragma unroll
      for (int ni=0;ni<8;ni++){
        int n = ni*16+lr;
        float y = (xv[ni]-mean)*inv*gcng[n] + gcnb[n];
        yv[ni]=y; s2+=y; ss2+=y*y;
        XG[(size_t)m*128+n] = f2bf(y);
        acc[mi][ni][r] = y;
      }
      #pragma unroll
      for (int mk=1;mk<16;mk<<=1){ s2 += __shfl_xor(s2,mk); ss2 += __shfl_xor(ss2,mk); }
      float mean2=s2*(1.f/128.f), var2=ss2*(1.f/128.f)-mean2*mean2, inv2=rsqrtf(fmaxf(var2,0.f)+1e-5f);
      #pragma unroll
      for (int ni=0;ni<8;ni++){
        int n = ni*16+lr;
        float t1 = (yv[ni]-mean2)*inv2*ln1g[n] + ln1b[n];
        As[ml*128 + (((n>>3)^(ml&7))*8) + (n&7)] = f2bf(t1);
      }
    }
  }
  __syncthreads();
  f32x4 acc2[2][8] = {};
  #pragma unroll
  for (int kk=0;kk<128;kk+=32){
    const int c = (kk>>3) + lh;
    short8 af[2], bfr[8];
    #pragma unroll
    for (int mi=0;mi<2;mi++){ int row=wm+mi*16+lr; af[mi]  = *(const short8*)&As[row*128 + ((c^(row&7))*8)]; }
    #pragma unroll
    for (int ni=0;ni<8;ni++){ int row=ni*16+lr;    bfr[ni] = *(const short8*)&Ws[row*128 + ((c^(row&7))*8)]; }
    #pragma unroll
    for (int mi=0;mi<2;mi++)
      #pragma unroll
      for (int ni=0;ni<8;ni++)
        acc2[mi][ni] = __builtin_amdgcn_mfma_f32_16x16x32_bf16(af[mi], bfr[ni], acc2[mi][ni], 0,0,0);
  }
  #pragma unroll
  for (int mi=0;mi<2;mi++){
    #pragma unroll
    for (int r=0;r<4;r++){
      const int m = m0 + wm + mi*16 + lh*4 + r;
      float hv[8]; float s=0.f, ss=0.f;
      #pragma unroll
      for (int ni=0;ni<8;ni++){
        int n = ni*16+lr;
        float h = acc2[mi][ni][r] + Ben[n] + acc[mi][ni][r];
        hv[ni]=h; s+=h; ss+=h*h;
      }
      #pragma unroll
      for (int mk=1;mk<16;mk<<=1){ s += __shfl_xor(s,mk); ss += __shfl_xor(ss,mk); }
      float mean=s*(1.f/128.f), var=ss*(1.f/128.f)-mean*mean, inv=rsqrtf(fmaxf(var,0.f)+1e-5f);
      #pragma unroll
      for (int ni=0;ni<8;ni++){
        int n = ni*16+lr;
        T2[(size_t)m*128+n] = f2bf((hv[ni]-mean)*inv*ln2g[n] + ln2b[n]);
        P [(size_t)m*128+n] = f2bf(acc[mi][ni][r] + hv[ni]);
      }
    }
  }
}

// ---------------------------------------------------------------------------
// Fused FFN v3: S = P + relu(T2 @ W1 + b1) @ W2 + b2
// 128 rows/block, 8 waves x 16 rows (GEMM1). The A-operand (T2, chunk-
// invariant) lives in 4 short8 REGISTERS per lane (byte-identical fragments
// to the former LDS reads) -> no As buffer. LDS = W1s 16K + W2s 16K +
// Hs 16K = 48KB. Weight staging via global_load_lds (r7 scheme). VGPR ~75.
// ---------------------------------------------------------------------------
__global__ __launch_bounds__(512,4) void ffn_k(
    const ushort* __restrict__ T2, const ushort* __restrict__ W1t, const float* __restrict__ b1,
    const ushort* __restrict__ W2t, const float* __restrict__ b2,
    const ushort* __restrict__ P,
    ushort* __restrict__ S)
{
  __shared__ __align__(16) ushort W1s[64*128];  // 16KB
  __shared__ __align__(16) ushort W2s[128*64];  // 16KB
  __shared__ __align__(16) ushort Hs [128*64];  // 16KB
  const int t = threadIdx.x;
  const int m0 = blockIdx.x*128;
  const int w=t>>6, lane=t&63, lr=lane&15, lh=lane>>4;
  const int wm2=(w>>2)*64, wn2=(w&3)*32;   // GEMM2: 64x32 per wave
  const int mw = w*16 + lr;                // GEMM1: 16 rows per wave
  // T2 row -> registers (chunk-invariant A-operand of GEMM1)
  short8 af[4];
  #pragma unroll
  for (int kki=0;kki<4;kki++)
    af[kki] = *(const short8*)(T2 + (size_t)(m0+mw)*128 + kki*32 + lh*8);
  f32x4 acc2[4][2] = {};
  for (int ch=0; ch<32; ++ch){
    __syncthreads();                       // prev-chunk readers done
    #pragma unroll
    for (int i=0;i<2;i++){
      int f=i*512+t; int r=f>>4, c=f&15;
      gld_lds16(W1t + (size_t)(ch*64+r)*128 + ((c^(r&7))*8), &W1s[f*8]);
    }
    #pragma unroll
    for (int i=0;i<2;i++){
      int f=i*512+t; int r=f>>3, c=f&7;
      gld_lds16(W2t + (size_t)r*2048 + ch*64 + ((c^(r&7))*8), &W2s[f*8]);
    }
    __syncthreads();                       // staged weights visible
    // GEMM1 (swapped): a1[ni] = W1(rows n1) x T2regs -> C[n1][m]
    f32x4 a1[4] = {};
    #pragma unroll
    for (int kki=0;kki<4;kki++){
      const int c = kki*4 + lh;
      #pragma unroll
      for (int ni=0;ni<4;ni++){
        int nr = ni*16 + lr;
        short8 wf = *(const short8*)&W1s[nr*128 + ((c^(nr&7))*8)];
        a1[ni] = __builtin_amdgcn_mfma_f32_16x16x32_bf16(wf, af[kki], a1[ni],0,0,0);
      }
    }
    // bias+relu+pack -> Hs (swizzled b64 writes)
    {
      const unsigned int msw = (unsigned int)((mw&7)<<4);
      #pragma unroll
      for (int ni=0;ni<4;ni++){
        float v0 = fmaxf(a1[ni][0] + b1[ch*64 + ni*16 + lh*4 + 0], 0.f);
        float v1 = fmaxf(a1[ni][1] + b1[ch*64 + ni*16 + lh*4 + 1], 0.f);
        float v2 = fmaxf(a1[ni][2] + b1[ch*64 + ni*16 + lh*4 + 2], 0.f);
        float v3 = fmaxf(a1[ni][3] + b1[ch*64 + ni*16 + lh*4 + 3], 0.f);
        uint2 p;
        p.x = f2bf2(v0, v1);
        p.y = f2bf2(v2, v3);
        *(uint2*)((char*)Hs + mw*128 + (((unsigned int)(ni*32 + lh*8)) ^ msw)) = p;
      }
    }
    __syncthreads();                       // Hs visible cross-wave
    #pragma unroll
    for (int kk=0;kk<64;kk+=32){
      const int c = (kk>>3) + lh;
      short8 af2[4], bf2r[2];
      #pragma unroll
      for (int mi=0;mi<4;mi++){
        int mr = wm2 + mi*16 + lr;
        af2[mi] = *(const short8*)((const char*)Hs + mr*128 + (((unsigned int)(c*16)) ^ ((unsigned int)((mr&7)<<4))));
      }
      #pragma unroll
      for (int ni=0;ni<2;ni++){
        int nr = wn2 + ni*16 + lr;
        bf2r[ni] = *(const short8*)&W2s[nr*64 + ((c^(nr&7))*8)];
      }
      #pragma unroll
      for (int mi=0;mi<4;mi++)
        #pragma unroll
        for (int ni=0;ni<2;ni++)
          acc2[mi][ni] = __builtin_amdgcn_mfma_f32_16x16x32_bf16(af2[mi], bf2r[ni], acc2[mi][ni],0,0,0);
    }
  }
  #pragma unroll
  for (int mi=0;mi<4;mi++)
    #pragma unroll
    for (int ni=0;ni<2;ni++)
      #pragma unroll
      for (int r=0;r<4;r++){
        int m = m0 + wm2 + mi*16 + lh*4 + r;
        int n = wn2 + ni*16 + lr;
        float v = acc2[mi][ni][r] + b2[n] + bf2f(P[(size_t)m*128+n]);
        S[(size_t)m*128+n] = f2bf(v);
      }
}

// ---------------------------------------------------------------------------
// group-LN(128) then add Gc then global-LN(1024); wave per row
// ---------------------------------------------------------------------------
__global__ void ln_cg_k(const ushort* __restrict__ S, const ushort* __restrict__ Gc,
    const float* __restrict__ gsg, const float* __restrict__ gsb,
    const float* __restrict__ glg, const float* __restrict__ glb,
    ushort* __restrict__ O, int nrows)
{
  int gw = (int)((blockIdx.x*blockDim.x + threadIdx.x)>>6);
  int lane = threadIdx.x & 63;
  int nw = (int)((gridDim.x*blockDim.x)>>6);
  for (int row=gw; row<nrows; row+=nw){
    size_t base = (size_t)row*1024 + (size_t)lane*16;
    float x[16];
    short8 v0 = *(const short8*)(S+base);
    short8 v1 = *(const short8*)(S+base+8);
    #pragma unroll
    for (int i=0;i<8;i++){ x[i]=bf2f((ushort)v0[i]); x[8+i]=bf2f((ushort)v1[i]); }
    float s=0, ss=0;
    #pragma unroll
    for (int i=0;i<16;i++){ s+=x[i]; ss+=x[i]*x[i]; }
    #pragma unroll
    for (int mk=1;mk<8;mk<<=1){ s+=__shfl_xor(s,mk); ss+=__shfl_xor(ss,mk); }
    float mean=s*(1.f/128.f), var=ss*(1.f/128.f)-mean*mean, inv=rsqrtf(fmaxf(var,0.f)+1e-5f);
    int j0=(lane&7)*16;
    short8 gc0 = *(const short8*)(Gc+base);
    short8 gc1 = *(const short8*)(Gc+base+8);
    float z[16];
    #pragma unroll
    for (int i=0;i<16;i++){
      float y = (x[i]-mean)*inv*gsg[j0+i] + gsb[j0+i];
      z[i] = y + bf2f((ushort)(i<8? gc0[i] : gc1[i-8]));
    }
    s=0; ss=0;
    #pragma unroll
    for (int i=0;i<16;i++){ s+=z[i]; ss+=z[i]*z[i]; }
    #pragma unroll
    for (int mk=1;mk<64;mk<<=1){ s+=__shfl_xor(s,mk); ss+=__shfl_xor(ss,mk); }
    mean = s*(1.f/1024.f); var = ss*(1.f/1024.f)-mean*mean; inv = rsqrtf(fmaxf(var,0.f)+1e-5f);
    int d0 = lane*16;
    float rr[16];
    #pragma unroll
    for (int i=0;i<16;i++) rr[i] = (z[i]-mean)*inv*glg[d0+i] + glb[d0+i];
    uint4 oa, ob;
    oa.x=f2bf2(rr[0],rr[1]);  oa.y=f2bf2(rr[2],rr[3]);
    oa.z=f2bf2(rr[4],rr[5]);  oa.w=f2bf2(rr[6],rr[7]);
    ob.x=f2bf2(rr[8],rr[9]);  ob.y=f2bf2(rr[10],rr[11]);
    ob.z=f2bf2(rr[12],rr[13]);ob.w=f2bf2(rr[14],rr[15]);
    *(uint4*)(O+base)   = oa;
    *(uint4*)(O+base+8) = ob;
  }
}

// ---------------------------------------------------------------------------
// Prep kernels
// ---------------------------------------------------------------------------
__global__ void freq_k(float* fr){
  int i = threadIdx.x;
  if (i < 512) fr[i] = expf((-9.210340371976184f/511.f) * (float)i);
}

__global__ void temb_k(const float* __restrict__ tt, const float* __restrict__ fr,
                       ushort* __restrict__ te){
  int idx = blockIdx.x*blockDim.x + threadIdx.x;
  int stride = gridDim.x*blockDim.x;
  for (; idx < 16384*512; idx += stride){
    int b = idx>>9, i = idx&511;
    float ang = tt[b]*fr[i];
    te[(size_t)b*1024 + i]       = f2bf(sinf(ang));
    te[(size_t)b*1024 + 512 + i] = f2bf(cosf(ang));
  }
}

__global__ void cvt_k(const float* __restrict__ in, ushort* __restrict__ out, size_t n4){
  size_t i = (size_t)blockIdx.x*blockDim.x + threadIdx.x;
  size_t st = (size_t)gridDim.x*blockDim.x;
  for (; i<n4; i+=st){
    const float4 v = ((const float4*)in)[i];
    uint2 o; o.x = f2bf2(v.x, v.y); o.y = f2bf2(v.z, v.w);
    ((uint2*)out)[i] = o;
  }
}

// transpose+convert: in [bz][R][C] f32 -> out [bz][C][R] bf16
__global__ void tcvt_k(const float* __restrict__ in, ushort* __restrict__ out,
                       int R, int C, long in_bs, long out_bs){
  __shared__ float tile[32][33];
  const int bz = blockIdx.z;
  const int r0 = blockIdx.y*32, c0 = blockIdx.x*32;
  const int tx = threadIdx.x & 31, ty = threadIdx.x >> 5;
  const float* ip = in + (size_t)bz*in_bs;
  ushort* op = out + (size_t)bz*out_bs;
  #pragma unroll
  for (int i=0;i<32;i+=8) tile[ty+i][tx] = ip[(size_t)(r0+ty+i)*C + c0+tx];
  __syncthreads();
  #pragma unroll
  for (int i=0;i<32;i+=8) op[(size_t)(c0+ty+i)*R + r0+tx] = f2bf(tile[tx][ty+i]);
}

// parallel Wv@Wo collapse: grid (12, 128) -> (pair, k-row); 128 threads = n
__global__ __launch_bounds__(128) void comb_small_k(
     const float* __restrict__ wvA, const float* __restrict__ woA,
     const float* __restrict__ bvA, const float* __restrict__ boA,
     const float* __restrict__ wvB, const float* __restrict__ woB,
     const float* __restrict__ bvB, const float* __restrict__ boB,
     ushort* __restrict__ voA, float* __restrict__ cbA,
     ushort* __restrict__ voB, float* __restrict__ cbB)
{
  const int pair = blockIdx.x;
  const int l = pair >> 1, which = pair & 1;
  const int k = blockIdx.y;
  const int n = threadIdx.x;
  const float* wv = (which? wvB:wvA) + (size_t)l*16384;
  const float* wo = (which? woB:woA) + (size_t)l*16384;
  ushort* vo = (which? voB:voA) + (size_t)l*16384;
  float acc = 0.f;
  #pragma unroll 8
  for (int j=0;j<128;j++) acc += wv[k*128+j]*wo[j*128+n];
  vo[(size_t)n*128 + k] = f2bf(acc);
  if (k == 0){
    const float* bv = (which? bvB:bvA) + l*128;
    const float* bo = (which? boB:boA) + l*128;
    float a2 = 0.f;
    #pragma unroll 8
    for (int kk=0;kk<128;kk++) a2 += bv[kk]*wo[kk*128+n];
    float* cb = (which? cbB:cbA) + l*128;
    cb[n] = a2 + bo[n];
  }
}

// cb[l][n] = sum_k bv[l][k]*wo[l][k][n] + bo[l][n]
__global__ __launch_bounds__(256) void glob_bias_k(
    const float* __restrict__ bv, const float* __restrict__ wo,
    const float* __restrict__ bo, float* __restrict__ cb){
  __shared__ float red[256];
  const int l = blockIdx.y;
  const int nl = threadIdx.x & 63;
  const int ks = threadIdx.x >> 6;
  const int n = blockIdx.x*64 + nl;
  const float* wol = wo + (size_t)l*1048576;
  float acc = 0.f;
  for (int k=ks*256; k<ks*256+256; ++k) acc += bv[l*1024+k]*wol[(size_t)k*1024+n];
  red[threadIdx.x] = acc;
  __syncthreads();
  if (ks == 0){
    float v = red[nl] + red[nl+64] + red[nl+128] + red[nl+192];
    cb[l*1024+n] = v + bo[l*1024+n];
  }
}

// ---------------------------------------------------------------------------
extern "C" void kernel_launch(void* const* d_in, const int* in_sizes, int n_in,
                              void* d_out, int out_size, void* d_ws, size_t ws_size,
                              hipStream_t stream)
{
  const float* x    = (const float*)d_in[0];
  const float* tt   = (const float*)d_in[1];
  const int*   uid  = (const int*)d_in[2];
  const int*   scr  = (const int*)d_in[3];
  const float* utab = (const float*)d_in[4];
  const float* stab = (const float*)d_in[5];
  const float* tp_w1=(const float*)d_in[6];
  const float* tp_b1=(const float*)d_in[7];
  const float* tp_w2=(const float*)d_in[8];
  const float* tp_b2=(const float*)d_in[9];
  const float* gp_w =(const float*)d_in[10];
  const float* gp_b =(const float*)d_in[11];
  const float* gca_wv=(const float*)d_in[14];
  const float* gca_wo=(const float*)d_in[15];
  const float* gca_bv=(const float*)d_in[18];
  const float* gca_bo=(const float*)d_in[19];
  const float* enc_wv=(const float*)d_in[22];
  const float* enc_wo=(const float*)d_in[23];
  const float* enc_bv=(const float*)d_in[26];
  const float* enc_bo=(const float*)d_in[27];
  const float* glob_wv=(const float*)d_in[30];
  const float* glob_wo=(const float*)d_in[31];
  const float* glob_bv=(const float*)d_in[34];
  const float* glob_bo=(const float*)d_in[35];
  const float* ln1_g=(const float*)d_in[36];
  const float* ln1_b=(const float*)d_in[37];
  const float* ln2_g=(const float*)d_in[38];
  const float* ln2_b=(const float*)d_in[39];
  const float* gcn_g=(const float*)d_in[40];
  const float* gcn_b=(const float*)d_in[41];
  const float* gsn_g=(const float*)d_in[42];
  const float* gsn_b=(const float*)d_in[43];
  const float* gln_g=(const float*)d_in[44];
  const float* gln_b=(const float*)d_in[45];
  const float* ff_w1=(const float*)d_in[46];
  const float* ff_b1=(const float*)d_in[47];
  const float* ff_w2=(const float*)d_in[48];
  const float* ff_b2=(const float*)d_in[49];
  const float* op_w1=(const float*)d_in[50];
  const float* op_b1=(const float*)d_in[51];
  const float* op_w2=(const float*)d_in[52];
  const float* op_b2=(const float*)d_in[53];

  char* ws = (char*)d_ws;
  size_t off = 0;
  auto alloc = [&](size_t bytes)->char*{ char* p = ws+off; off += (bytes+255)&~(size_t)255; return p; };

  // ---- persistent region ----
  ushort* W_gt   = (ushort*)alloc(1024UL*1024*2);
  ushort* W_ff1t = (ushort*)alloc(6UL*2048*128*2);
  ushort* W_ff2t = (ushort*)alloc(6UL*128*2048*2);
  ushort* W_gvo  = (ushort*)alloc(6UL*1024*1024*2);
  ushort* W_cvo  = (ushort*)alloc(6UL*128*128*2);
  ushort* W_evo  = (ushort*)alloc(6UL*128*128*2);
  float*  B_cca  = (float*)alloc(6UL*128*4);
  float*  B_cen  = (float*)alloc(6UL*128*4);
  float*  B_cgl  = (float*)alloc(6UL*1024*4);
  float*  F_freq = (float*)alloc(512*4);
  ushort* A_cond = (ushort*)alloc(16384UL*1024*2);
  ushort* A_cg   = (ushort*)alloc(16384UL*1024*2);
  ushort* A_xg   = (ushort*)alloc(16384UL*1024*2);
  ushort* S0 = (ushort*)alloc(16384UL*1024*2);
  ushort* S1 = (ushort*)alloc(16384UL*1024*2);
  ushort* SD = (ushort*)d_out;
  (void)ws_size; (void)in_sizes; (void)n_in; (void)out_size;

  // aliases
  ushort* A_te   = S0;
  ushort* W_tp1t = S1;
  ushort* W_tp2t = S1 + 4194304;
  ushort* H1     = SD;                 // 64 MB: 8192 x 4096 bf16
  ushort* A_xbf  = S0;
  ushort* W_gwot = S1;
  ushort* W_gwv  = S1 + 6291456;
  ushort* W_op1t = W_gvo;
  ushort* W_op2t = W_gvo + 2097152;
  ushort* O1     = S0;                 // 64 MB spanning S0+S1

  // ---- phase 1: time embedding + MLP (2 chunks of 8192 rows) ----
  hipLaunchKernelGGL(freq_k, dim3(1), dim3(512), 0, stream, F_freq);
  hipLaunchKernelGGL(temb_k, dim3(4096), dim3(256), 0, stream, tt, F_freq, A_te);
  hipLaunchKernelGGL(tcvt_k, dim3(128,32,1), dim3(256), 0, stream, tp_w1, W_tp1t, 1024, 4096, 0L, 0L);
  hipLaunchKernelGGL(tcvt_k, dim3(32,128,1), dim3(256), 0, stream, tp_w2, W_tp2t, 4096, 1024, 0L, 0L);
  for (int c=0;c<2;c++){
    hipLaunchKernelGGL((gemm_k<EPI_GELU,false>), dim3(32,64), dim3(256), 0, stream,
        A_te + (size_t)c*8192*1024, W_tp1t, (void*)H1, tp_b1,
        (const ushort*)nullptr,(const int*)nullptr,(const int*)nullptr,
        (const float*)nullptr,(const float*)nullptr, 8192,4096,1024,4096, 0L,0L,0L);
    hipLaunchKernelGGL((gemm_k<EPI_COND,false>), dim3(8,64), dim3(256), 0, stream,
        H1, W_tp2t, (void*)(A_cond + (size_t)c*8192*1024), tp_b2,
        (const ushort*)nullptr, uid + c*8192, scr + c*8192, utab, stab,
        8192,1024,4096,1024, 0L,0L,0L);
  }

  // ---- phase 2: group projections of x and cond ----
  hipLaunchKernelGGL(tcvt_k, dim3(4,32,8), dim3(256), 0, stream, gp_w, W_gt, 1024, 128, (long)(1024*128), (long)(128*1024));
  hipLaunchKernelGGL(cvt_k, dim3(4096), dim3(256), 0, stream, x, A_xbf, (size_t)(16384UL*1024/4));
  hipLaunchKernelGGL((gemm_k<EPI_NONE,false>), dim3(8,128), dim3(256), 0, stream,
      A_xbf, W_gt, (void*)A_xg, gp_b, (const ushort*)nullptr,(const int*)nullptr,(const int*)nullptr,
      (const float*)nullptr,(const float*)nullptr, 16384,1024,1024,1024, 0L,0L,0L);
  hipLaunchKernelGGL((gemm_k<EPI_NONE,false>), dim3(8,128), dim3(256), 0, stream,
      A_cond, W_gt, (void*)A_cg, gp_b, (const ushort*)nullptr,(const int*)nullptr,(const int*)nullptr,
      (const float*)nullptr,(const float*)nullptr, 16384,1024,1024,1024, 0L,0L,0L);

  // ---- phase 3: collapsed attention weights ----
  hipLaunchKernelGGL(tcvt_k, dim3(32,32,6), dim3(256), 0, stream, glob_wo, W_gwot, 1024, 1024, (long)(1024*1024), (long)(1024*1024));
  hipLaunchKernelGGL(cvt_k, dim3(2048), dim3(256), 0, stream, glob_wv, W_gwv, (size_t)(6UL*1024*1024/4));
  hipLaunchKernelGGL((gemm_k<EPI_NONE,false>), dim3(8,8,6), dim3(256), 0, stream,
      W_gwot, W_gwv, (void*)W_gvo,
      (const float*)nullptr, (const ushort*)nullptr, (const int*)nullptr, (const int*)nullptr,
      (const float*)nullptr, (const float*)nullptr, 1024,1024,1024,1024,
      1048576L,1048576L,1048576L);
  hipLaunchKernelGGL(comb_small_k, dim3(12,128), dim3(128), 0, stream,
      gca_wv, gca_wo, gca_bv, gca_bo, enc_wv, enc_wo, enc_bv, enc_bo,
      W_cvo, B_cca, W_evo, B_cen);
  hipLaunchKernelGGL(glob_bias_k, dim3(16,6), dim3(256), 0, stream, glob_bv, glob_wo, glob_bo, B_cgl);
  hipLaunchKernelGGL(tcvt_k, dim3(64,4,6), dim3(256), 0, stream, ff_w1, W_ff1t, 128, 2048, (long)(128*2048), (long)(2048*128));
  hipLaunchKernelGGL(tcvt_k, dim3(4,64,6), dim3(256), 0, stream, ff_w2, W_ff2t, 2048, 128, (long)(2048*128), (long)(128*2048));

  // ---- layer loop ----
  for (int l=0;l<6;l++){
    ushort* T2 = S0; ushort* SS = S1; ushort* XGL = S0;
    ushort* P  = SD;
    ushort* GC = SD + 16777216;
    hipLaunchKernelGGL(enc_fused_k, dim3(1024), dim3(256), 0, stream,
      A_cg, W_cvo + (size_t)l*16384, B_cca + l*128,
      W_evo + (size_t)l*16384, B_cen + l*128,
      A_xg,
      gcn_g+l*128, gcn_b+l*128, ln1_g+l*128, ln1_b+l*128, ln2_g+l*128, ln2_b+l*128,
      P, T2);
    hipLaunchKernelGGL(ffn_k, dim3(1024), dim3(512), 0, stream,
      T2, W_ff1t + (size_t)l*262144, ff_b1 + l*2048, W_ff2t + (size_t)l*262144, ff_b2 + l*128,
      P, SS);
    hipLaunchKernelGGL((gemm_k<EPI_NONE,false>), dim3(8,128), dim3(256), 0, stream,
      A_cond, W_gvo + (size_t)l*1048576, (void*)GC, B_cgl + l*1024,
      (const ushort*)nullptr,(const int*)nullptr,(const int*)nullptr,(const float*)nullptr,(const float*)nullptr,
      16384,1024,1024,1024, 0L,0L,0L);
    hipLaunchKernelGGL(ln_cg_k, dim3(512), dim3(256), 0, stream,
      SS, GC, gsn_g+l*128, gsn_b+l*128, gln_g+l*1024, gln_b+l*1024, XGL, 16384);
    hipLaunchKernelGGL((gemm_k<EPI_NONE,false>), dim3(8,128), dim3(256), 0, stream,
      XGL, W_gt, (void*)A_xg, gp_b,
      (const ushort*)nullptr,(const int*)nullptr,(const int*)nullptr,(const float*)nullptr,(const float*)nullptr,
      16384,1024,1024,1024, 0L,0L,0L);
  }

  // ---- output MLP ----
  hipLaunchKernelGGL(tcvt_k, dim3(64,32,1), dim3(256), 0, stream, op_w1, W_op1t, 1024, 2048, 0L, 0L);
  hipLaunchKernelGGL(tcvt_k, dim3(32,64,1), dim3(256), 0, stream, op_w2, W_op2t, 2048, 1024, 0L, 0L);
  hipLaunchKernelGGL((gemm_k<EPI_GELU,false>), dim3(16,128), dim3(256), 0, stream,
      A_xg, W_op1t, (void*)O1, op_b1,
      (const ushort*)nullptr,(const int*)nullptr,(const int*)nullptr,(const float*)nullptr,(const float*)nullptr,
      16384,2048,1024,2048, 0L,0L,0L);
  hipLaunchKernelGGL((gemm_k<EPI_NONE,true>), dim3(8,128), dim3(256), 0, stream,
      O1, W_op2t, d_out, op_b2,
      (const ushort*)nullptr,(const int*)nullptr,(const int*)nullptr,(const float*)nullptr,(const float*)nullptr,
      16384,1024,2048,1024, 0L,0L,0L);
}